// Round 1
// baseline (580.344 us; speedup 1.0000x reference)
//
#include <hip/hip_runtime.h>
#include <hip/hip_bf16.h>

namespace {
constexpr int P       = 20001;   // MOVIES + 1 (padding row)
constexpr int NGENRES = 20;
constexpr int NTAGS   = 1000;
constexpr int NGTAGS  = 1128;
constexpr int NB      = 1024;
constexpr int NH      = 50;
constexpr int PHID    = 256;
constexpr int OD      = 128;
constexpr int EG = 8, ET = 16, EGT = 16, EM = 32, EY = 8, EUG = 32, ETS = 4;
constexpr int PAD  = 20000;
constexpr int MT   = 16;     // movies per block in tower kernel
constexpr int CATD = 80;     // EG+ET+EGT+EM+EY
}

// ---------------------------------------------------------------------------
// Kernel 1: item_tower for ALL 20001 movies -> T[P][128], plus genome tower
// tanh output -> GT[P][16]. One block = 16 movies, 256 threads.
// ---------------------------------------------------------------------------
__global__ __launch_bounds__(256) void movie_tower_kernel(
    const float* __restrict__ genome_ctx, const float* __restrict__ genre_ctx,
    const float* __restrict__ tag_ctx,    const int*   __restrict__ year_ctx,
    const float* __restrict__ item_emb,   const float* __restrict__ year_tab,
    const float* __restrict__ w_item,  const float* __restrict__ b_item,
    const float* __restrict__ w_genre, const float* __restrict__ b_genre,
    const float* __restrict__ w_tag,   const float* __restrict__ b_tag,
    const float* __restrict__ w_genome,const float* __restrict__ b_genome,
    const float* __restrict__ w_year,  const float* __restrict__ b_year,
    const float* __restrict__ w_ip1,   const float* __restrict__ b_ip1,
    const float* __restrict__ w_ip2,   const float* __restrict__ b_ip2,
    float* __restrict__ T, float* __restrict__ GT)
{
  __shared__ float s_cat[MT][CATD];                 // 5 KB
  __shared__ float s_h[MT][PHID];                   // 16 KB
  __shared__ __align__(16) float s_part[4][MT][16]; // 4 KB  (k-split partials)
  __shared__ int   s_ids[MT];

  const int t   = threadIdx.x;
  const int blk = blockIdx.x;

  if (t < MT) {
    int movie = blk * MT + t;
    s_ids[t] = movie < P ? movie : (P - 1);
  }
  __syncthreads();

  const int m  = t >> 4;        // 0..15 movie slot
  const int j  = t & 15;        // 0..15 output col (for 16-wide towers)
  const int jq = (t >> 2) & 3;  // 0..3  col quad
  const int ks = t & 3;         // 0..3  k-split

  // ---- tag tower: (1000) @ (1000,16), k-split by 4, 4 cols/thread ----
  {
    const float* row = tag_ctx + (long)s_ids[m] * NTAGS;
    float a0 = 0.f, a1 = 0.f, a2 = 0.f, a3 = 0.f;
    const int kq = NTAGS / 4;               // 250
    const int k0 = ks * kq, k1 = k0 + kq;
    for (int k = k0; k < k1; ++k) {
      float a = row[k];
      const float4 w4 = *(const float4*)(w_tag + k * ET + jq * 4);
      a0 += a * w4.x; a1 += a * w4.y; a2 += a * w4.z; a3 += a * w4.w;
    }
    *(float4*)&s_part[ks][m][jq * 4] = make_float4(a0, a1, a2, a3);
  }
  __syncthreads();
  {
    float s = b_tag[j] + s_part[0][m][j] + s_part[1][m][j]
                       + s_part[2][m][j] + s_part[3][m][j];
    s_cat[m][EG + j] = tanhf(s);
  }
  __syncthreads();

  // ---- genome tower: (1128) @ (1128,16) ----
  {
    const float* row = genome_ctx + (long)s_ids[m] * NGTAGS;
    float a0 = 0.f, a1 = 0.f, a2 = 0.f, a3 = 0.f;
    const int kq = NGTAGS / 4;              // 282
    const int k0 = ks * kq, k1 = k0 + kq;
    for (int k = k0; k < k1; ++k) {
      float a = row[k];
      const float4 w4 = *(const float4*)(w_genome + k * EGT + jq * 4);
      a0 += a * w4.x; a1 += a * w4.y; a2 += a * w4.z; a3 += a * w4.w;
    }
    *(float4*)&s_part[ks][m][jq * 4] = make_float4(a0, a1, a2, a3);
  }
  __syncthreads();
  {
    float s = b_genome[j] + s_part[0][m][j] + s_part[1][m][j]
                          + s_part[2][m][j] + s_part[3][m][j];
    float v = tanhf(s);
    s_cat[m][EG + ET + j] = v;
    int movie = blk * MT + m;
    if (movie < P) GT[movie * EGT + j] = v;   // genome pool table
  }

  // ---- item-emb tower: (32) @ (32,32), 2 cols/thread ----
  {
    const float* e = item_emb + (long)s_ids[m] * EM;
    float a0 = b_item[j], a1 = b_item[j + 16];
    #pragma unroll
    for (int k = 0; k < EM; ++k) {
      float ev = e[k];
      a0 += ev * w_item[k * EM + j];
      a1 += ev * w_item[k * EM + j + 16];
    }
    s_cat[m][EG + ET + EGT + j]      = tanhf(a0);
    s_cat[m][EG + ET + EGT + 16 + j] = tanhf(a1);
  }

  // ---- genre tower (threads 0..127) / year tower (threads 128..255) ----
  if (t < 128) {
    const int mm = t >> 3, jj = t & 7;
    const float* row = genre_ctx + (long)s_ids[mm] * NGENRES;
    float a = b_genre[jj];
    #pragma unroll
    for (int k = 0; k < NGENRES; ++k) a += row[k] * w_genre[k * EG + jj];
    s_cat[mm][jj] = tanhf(a);
  } else {
    const int u = t - 128;
    const int mm = u >> 3, jj = u & 7;
    const int yr = year_ctx[s_ids[mm]];
    float a = b_year[jj];
    #pragma unroll
    for (int k = 0; k < EY; ++k) a += year_tab[yr * EY + k] * w_year[k * EY + jj];
    s_cat[mm][EG + ET + EGT + EM + jj] = tanhf(a);
  }
  __syncthreads();

  // ---- ip1: (16,80) @ (80,256) -> relu -> s_h. Thread = 4 movies x 4 cols ----
  const int mq = t >> 6;   // 0..3 -> movies 4*mq..4*mq+3
  const int c  = t & 63;   // cols c, c+64, c+128, c+192
  {
    float acc[4][4];
    #pragma unroll
    for (int i = 0; i < 4; ++i) {
      float bv = b_ip1[c + 64 * i];
      #pragma unroll
      for (int mm = 0; mm < 4; ++mm) acc[i][mm] = bv;
    }
    for (int k = 0; k < CATD; ++k) {
      const float* wr = w_ip1 + k * PHID + c;
      float w0 = wr[0], w1 = wr[64], w2 = wr[128], w3 = wr[192];
      #pragma unroll
      for (int mm = 0; mm < 4; ++mm) {
        float cv = s_cat[mq * 4 + mm][k];
        acc[0][mm] += w0 * cv; acc[1][mm] += w1 * cv;
        acc[2][mm] += w2 * cv; acc[3][mm] += w3 * cv;
      }
    }
    #pragma unroll
    for (int i = 0; i < 4; ++i)
      #pragma unroll
      for (int mm = 0; mm < 4; ++mm)
        s_h[mq * 4 + mm][c + 64 * i] = fmaxf(acc[i][mm], 0.f);
  }
  __syncthreads();

  // ---- ip2: (16,256) @ (256,128) -> T. Thread = 4 movies x 2 cols ----
  {
    float o0[4], o1[4];
    float bv0 = b_ip2[c], bv1 = b_ip2[c + 64];
    #pragma unroll
    for (int mm = 0; mm < 4; ++mm) { o0[mm] = bv0; o1[mm] = bv1; }
    for (int k = 0; k < PHID; ++k) {
      float w0 = w_ip2[k * OD + c];
      float w1 = w_ip2[k * OD + c + 64];
      #pragma unroll
      for (int mm = 0; mm < 4; ++mm) {
        float hv = s_h[mq * 4 + mm][k];
        o0[mm] += w0 * hv; o1[mm] += w1 * hv;
      }
    }
    #pragma unroll
    for (int mm = 0; mm < 4; ++mm) {
      int movie = blk * MT + mq * 4 + mm;
      if (movie < P) {
        T[(long)movie * OD + c]      = o0[mm];
        T[(long)movie * OD + c + 64] = o1[mm];
      }
    }
  }
}

// ---------------------------------------------------------------------------
// Kernel 2: per-user pooling + user MLP + final dot. One block per user.
// ---------------------------------------------------------------------------
__global__ __launch_bounds__(256) void user_kernel(
    const float* __restrict__ ugc, const int* __restrict__ hist,
    const float* __restrict__ ratings, const int* __restrict__ tstamps,
    const int* __restrict__ target, const float* __restrict__ ts_tab,
    const float* __restrict__ w_ugenre, const float* __restrict__ b_ugenre,
    const float* __restrict__ w_ts, const float* __restrict__ b_ts,
    const float* __restrict__ w_up1, const float* __restrict__ b_up1,
    const float* __restrict__ w_up2, const float* __restrict__ b_up2,
    const float* __restrict__ T, const float* __restrict__ GT,
    float* __restrict__ out)
{
  __shared__ float s_w[NH];
  __shared__ int   s_ids[NH];
  __shared__ float s_cat[OD + EGT + EUG + ETS];   // 180
  __shared__ float s_h[PHID];
  __shared__ float s_inv;
  __shared__ float s_red[2];

  const int b = blockIdx.x, t = threadIdx.x;

  if (t < NH) {
    int id  = hist[b * NH + t];
    float r = ratings[b * NH + t];
    s_ids[t] = id;
    s_w[t]   = (id != PAD) ? r : 0.f;
  }
  __syncthreads();
  if (t == 0) {
    float s = 0.f;
    for (int h = 0; h < NH; ++h) s += fabsf(s_w[h]);
    s_inv = 1.f / fmaxf(s, 1e-6f);
  }
  __syncthreads();
  const float inv = s_inv;

  if (t < OD) {
    // item pool: weighted avg of T rows
    float acc = 0.f;
    for (int h = 0; h < NH; ++h)
      acc += s_w[h] * T[(long)s_ids[h] * OD + t];
    s_cat[t] = acc * inv;
  } else if (t < OD + EGT) {
    const int jj = t - OD;
    float acc = 0.f;
    for (int h = 0; h < NH; ++h)
      acc += s_w[h] * GT[s_ids[h] * EGT + jj];
    s_cat[OD + jj] = acc * inv;
  } else if (t < OD + EGT + EUG) {
    const int jj = t - (OD + EGT);
    float acc = b_ugenre[jj];
    #pragma unroll
    for (int k = 0; k < NGENRES; ++k)
      acc += ugc[b * NGENRES + k] * w_ugenre[k * EUG + jj];
    s_cat[OD + EGT + jj] = tanhf(acc);
  } else if (t < OD + EGT + EUG + ETS) {
    const int jj = t - (OD + EGT + EUG);
    const int ts = tstamps[b];
    float acc = b_ts[jj];
    #pragma unroll
    for (int k = 0; k < ETS; ++k)
      acc += ts_tab[ts * ETS + k] * w_ts[k * ETS + jj];
    s_cat[OD + EGT + EUG + jj] = tanhf(acc);
  }
  __syncthreads();

  // up1: (180) @ (180,256) + relu — every thread owns one hidden col
  {
    float acc = b_up1[t];
    for (int k = 0; k < OD + EGT + EUG + ETS; ++k)
      acc += s_cat[k] * w_up1[k * PHID + t];
    s_h[t] = fmaxf(acc, 0.f);
  }
  __syncthreads();

  // up2: (256) @ (256,128), then dot with item tower of target
  if (t < OD) {
    float acc = b_up2[t];
    for (int k = 0; k < PHID; ++k)
      acc += s_h[k] * w_up2[k * OD + t];
    float it = T[(long)target[b] * OD + t];
    float prod = acc * it;
    #pragma unroll
    for (int off = 32; off; off >>= 1) prod += __shfl_down(prod, off, 64);
    if ((t & 63) == 0) s_red[t >> 6] = prod;
  }
  __syncthreads();
  if (t == 0) out[b] = s_red[0] + s_red[1];
}

// ---------------------------------------------------------------------------
extern "C" void kernel_launch(void* const* d_in, const int* in_sizes, int n_in,
                              void* d_out, int out_size, void* d_ws, size_t ws_size,
                              hipStream_t stream) {
  const float* ugc      = (const float*)d_in[0];
  const int*   hist     = (const int*)  d_in[1];
  const float* ratings  = (const float*)d_in[2];
  const int*   tstamps  = (const int*)  d_in[3];
  const int*   target   = (const int*)  d_in[4];
  const float* genome   = (const float*)d_in[5];
  const float* genrec   = (const float*)d_in[6];
  const float* tagc     = (const float*)d_in[7];
  const int*   yearc    = (const int*)  d_in[8];
  const float* item_emb = (const float*)d_in[9];
  const float* year_tab = (const float*)d_in[10];
  const float* ts_tab   = (const float*)d_in[11];
  const float* w_item   = (const float*)d_in[12];
  const float* b_item   = (const float*)d_in[13];
  const float* w_genre  = (const float*)d_in[14];
  const float* b_genre  = (const float*)d_in[15];
  const float* w_tag    = (const float*)d_in[16];
  const float* b_tag    = (const float*)d_in[17];
  const float* w_genome = (const float*)d_in[18];
  const float* b_genome = (const float*)d_in[19];
  const float* w_year   = (const float*)d_in[20];
  const float* b_year   = (const float*)d_in[21];
  const float* w_ugenre = (const float*)d_in[22];
  const float* b_ugenre = (const float*)d_in[23];
  const float* w_ts     = (const float*)d_in[24];
  const float* b_ts     = (const float*)d_in[25];
  const float* w_up1    = (const float*)d_in[26];
  const float* b_up1    = (const float*)d_in[27];
  const float* w_up2    = (const float*)d_in[28];
  const float* b_up2    = (const float*)d_in[29];
  const float* w_ip1    = (const float*)d_in[30];
  const float* b_ip1    = (const float*)d_in[31];
  const float* w_ip2    = (const float*)d_in[32];
  const float* b_ip2    = (const float*)d_in[33];

  float* T  = (float*)d_ws;                                    // 20001*128 f32
  float* GT = (float*)((char*)d_ws + (size_t)P * OD * sizeof(float)); // 20001*16

  dim3 g1((P + MT - 1) / MT), blk(256);
  movie_tower_kernel<<<g1, blk, 0, stream>>>(
      genome, genrec, tagc, yearc, item_emb, year_tab,
      w_item, b_item, w_genre, b_genre, w_tag, b_tag, w_genome, b_genome,
      w_year, b_year, w_ip1, b_ip1, w_ip2, b_ip2, T, GT);

  user_kernel<<<dim3(NB), blk, 0, stream>>>(
      ugc, hist, ratings, tstamps, target, ts_tab,
      w_ugenre, b_ugenre, w_ts, b_ts, w_up1, b_up1, w_up2, b_up2,
      T, GT, (float*)d_out);
}

// Round 2
// 379.807 us; speedup vs baseline: 1.5280x; 1.5280x over previous
//
#include <hip/hip_runtime.h>
#include <hip/hip_bf16.h>

typedef __bf16 bf16x8 __attribute__((ext_vector_type(8)));
typedef float  f32x4  __attribute__((ext_vector_type(4)));

namespace {
constexpr int P       = 20001;   // MOVIES + 1 (padding row)
constexpr int NGENRES = 20;
constexpr int NTAGS   = 1000;
constexpr int NGTAGS  = 1128;
constexpr int NB      = 1024;
constexpr int NH      = 50;
constexpr int PHID    = 256;
constexpr int OD      = 128;
constexpr int EG = 8, ET = 16, EGT = 16, EM = 32, EY = 8, EUG = 32, ETS = 4;
constexpr int PAD  = 20000;
constexpr int MB   = 64;    // movies per block
constexpr int SA   = 72;    // LDS stride (bf16) for staged A/B chunks (pad vs banks)
constexpr int SC   = 104;   // s_cat stride (96 used: 80 + 16 zero pad)
constexpr int SH   = 264;   // s_h stride (256 used)
constexpr int CATD = 80;
}

// Skinny GEMM: gather-rows(ctx, ids)[64 x Kd] @ w[Kd x 16] via bf16 MFMA.
// Per wave: one 16x16 tile (movies wave*16..+15). Returns C in MFMA C-layout
// (col = lane&15, row = quad*4 + reg). fp32 global is converted to bf16 while
// staging into LDS with coalesced float4 loads.
static __device__ __forceinline__ f32x4 skinny16(
    const float* __restrict__ ctx, const int lda, const int Kd,
    const float* __restrict__ w, const float bias,
    const int* __restrict__ ids,
    __bf16 (*__restrict__ sa)[SA], __bf16 (*__restrict__ sbt)[SA],
    const int t, const int wave, const int l15, const int quad)
{
  f32x4 acc = {bias, bias, bias, bias};
  const int nchunk = (Kd + 63) >> 6;
  const int sm   = t >> 2;            // staging row 0..63
  const int sseg = (t & 3) << 4;      // k-seg 0,16,32,48
  const long rowbase = (long)ids[sm] * lda;
  const int bk = t >> 2;              // B staging k 0..63
  const int bn = (t & 3) << 2;        // B staging n 0,4,8,12
  const int am = wave * 16 + l15;

  for (int c = 0; c < nchunk; ++c) {
    const int k0 = c << 6;
    // stage A chunk [64][64] fp32 -> bf16 (coalesced float4, zero-pad tail)
    #pragma unroll
    for (int i = 0; i < 4; ++i) {
      const int k = k0 + sseg + (i << 2);
      float4 v;
      if (k + 4 <= Kd) {
        v = *(const float4*)(ctx + rowbase + k);
      } else {
        v.x = (k + 0 < Kd) ? ctx[rowbase + k + 0] : 0.f;
        v.y = (k + 1 < Kd) ? ctx[rowbase + k + 1] : 0.f;
        v.z = (k + 2 < Kd) ? ctx[rowbase + k + 2] : 0.f;
        v.w = (k + 3 < Kd) ? ctx[rowbase + k + 3] : 0.f;
      }
      __bf16* dst = &sa[sm][sseg + (i << 2)];
      dst[0] = (__bf16)v.x; dst[1] = (__bf16)v.y;
      dst[2] = (__bf16)v.z; dst[3] = (__bf16)v.w;
    }
    // stage B chunk transposed: sbt[n][k-k0]
    {
      const int k = k0 + bk;
      float4 v = make_float4(0.f, 0.f, 0.f, 0.f);
      if (k < Kd) v = *(const float4*)(w + k * 16 + bn);
      sbt[bn + 0][bk] = (__bf16)v.x;
      sbt[bn + 1][bk] = (__bf16)v.y;
      sbt[bn + 2][bk] = (__bf16)v.z;
      sbt[bn + 3][bk] = (__bf16)v.w;
    }
    __syncthreads();
    // 2 MFMAs (K=64). A-frag: A[m=lane&15][k=quad*8+j]; B-frag: B[k][n=lane&15]
    bf16x8 a0 = *(const bf16x8*)&sa[am][quad * 8];
    bf16x8 b0 = *(const bf16x8*)&sbt[l15][quad * 8];
    acc = __builtin_amdgcn_mfma_f32_16x16x32_bf16(a0, b0, acc, 0, 0, 0);
    bf16x8 a1 = *(const bf16x8*)&sa[am][32 + quad * 8];
    bf16x8 b1 = *(const bf16x8*)&sbt[l15][32 + quad * 8];
    acc = __builtin_amdgcn_mfma_f32_16x16x32_bf16(a1, b1, acc, 0, 0, 0);
    __syncthreads();
  }
  return acc;
}

// ---------------------------------------------------------------------------
// Kernel 1: item_tower for ALL movies via MFMA. Block = 256 thr = 4 waves,
// 64 movies. Outputs T[P][128] fp32 and GT[P][16] fp32.
// ---------------------------------------------------------------------------
__global__ __launch_bounds__(256) void movie_tower_kernel(
    const float* __restrict__ genome_ctx, const float* __restrict__ genre_ctx,
    const float* __restrict__ tag_ctx,    const int*   __restrict__ year_ctx,
    const float* __restrict__ item_emb,   const float* __restrict__ year_tab,
    const float* __restrict__ w_item,  const float* __restrict__ b_item,
    const float* __restrict__ w_genre, const float* __restrict__ b_genre,
    const float* __restrict__ w_tag,   const float* __restrict__ b_tag,
    const float* __restrict__ w_genome,const float* __restrict__ b_genome,
    const float* __restrict__ w_year,  const float* __restrict__ b_year,
    const float* __restrict__ w_ip1,   const float* __restrict__ b_ip1,
    const float* __restrict__ w_ip2,   const float* __restrict__ b_ip2,
    float* __restrict__ T, float* __restrict__ GT)
{
  struct Phase1 { __bf16 a[MB][SA]; __bf16 bt[16][SA]; };
  union ShU { Phase1 p1; __bf16 h[MB][SH]; };
  __shared__ __align__(16) ShU u;                 // max(11.3 KB, 33 KB)
  __shared__ __align__(16) __bf16 s_cat[MB][SC];  // 13 KB
  __shared__ int s_ids[MB];

  const int t = threadIdx.x, blk = blockIdx.x;
  const int wave = t >> 6, lane = t & 63, l15 = lane & 15, quad = lane >> 4;

  if (t < MB) {
    int movie = blk * MB + t;
    s_ids[t] = movie < P ? movie : P - 1;
  }
  __syncthreads();

  // ---- tag tower (K=1000) ----
  {
    f32x4 acc = skinny16(tag_ctx, NTAGS, NTAGS, w_tag, b_tag[l15],
                         s_ids, u.p1.a, u.p1.bt, t, wave, l15, quad);
    #pragma unroll
    for (int r = 0; r < 4; ++r) {
      int m = wave * 16 + quad * 4 + r;
      s_cat[m][EG + l15] = (__bf16)tanhf(acc[r]);
    }
  }
  // ---- genome tower (K=1128), also emits GT ----
  {
    f32x4 acc = skinny16(genome_ctx, NGTAGS, NGTAGS, w_genome, b_genome[l15],
                         s_ids, u.p1.a, u.p1.bt, t, wave, l15, quad);
    #pragma unroll
    for (int r = 0; r < 4; ++r) {
      int m = wave * 16 + quad * 4 + r;
      float v = tanhf(acc[r]);
      s_cat[m][EG + ET + l15] = (__bf16)v;
      int movie = blk * MB + m;
      if (movie < P) GT[movie * EGT + l15] = v;
    }
  }

  // ---- small towers (fp32 vector, disjoint s_cat columns) ----
  #pragma unroll
  for (int i = 0; i < 2; ++i) {           // genre: 64 x 8
    int idx = t * 2 + i;
    int m = idx >> 3, j = idx & 7;
    const float* row = genre_ctx + (long)s_ids[m] * NGENRES;
    float a = b_genre[j];
    #pragma unroll
    for (int k = 0; k < NGENRES; ++k) a = fmaf(row[k], w_genre[k * EG + j], a);
    s_cat[m][j] = (__bf16)tanhf(a);
  }
  #pragma unroll
  for (int i = 0; i < 2; ++i) {           // year: 64 x 8
    int idx = t * 2 + i;
    int m = idx >> 3, j = idx & 7;
    int yr = year_ctx[s_ids[m]];
    float a = b_year[j];
    #pragma unroll
    for (int k = 0; k < EY; ++k)
      a = fmaf(year_tab[yr * EY + k], w_year[k * EY + j], a);
    s_cat[m][EG + ET + EGT + EM + j] = (__bf16)tanhf(a);
  }
  {                                       // item emb: 64 x 32
    int m = t >> 2, j0 = (t & 3) * 8;
    const float* e = item_emb + (long)s_ids[m] * EM;
    float a[8];
    #pragma unroll
    for (int i = 0; i < 8; ++i) a[i] = b_item[j0 + i];
    for (int k = 0; k < EM; ++k) {
      float ev = e[k];
      #pragma unroll
      for (int i = 0; i < 8; ++i) a[i] = fmaf(ev, w_item[k * EM + j0 + i], a[i]);
    }
    #pragma unroll
    for (int i = 0; i < 8; ++i)
      s_cat[m][EG + ET + EGT + j0 + i] = (__bf16)tanhf(a[i]);
  }
  #pragma unroll
  for (int i = 0; i < 4; ++i) {           // zero K-pad cols 80..95
    int idx = i * 256 + t;
    int m = idx >> 4, k = CATD + (idx & 15);
    s_cat[m][k] = (__bf16)0.f;
  }
  __syncthreads();

  // ---- ip1 MFMA: [64,96] @ [96,256] -> relu -> u.h (bf16) ----
  {
    bf16x8 bfr[4][3];                     // B-frags, wave owns cols wave*64..+63
    #pragma unroll
    for (int nt = 0; nt < 4; ++nt) {
      const int n = wave * 64 + nt * 16 + l15;
      #pragma unroll
      for (int kc = 0; kc < 3; ++kc)
        #pragma unroll
        for (int j = 0; j < 8; ++j) {
          int k = kc * 32 + quad * 8 + j;
          bfr[nt][kc][j] = (__bf16)((k < CATD) ? w_ip1[k * PHID + n] : 0.f);
        }
    }
    #pragma unroll
    for (int mt = 0; mt < 4; ++mt) {
      bf16x8 af[3];
      #pragma unroll
      for (int kc = 0; kc < 3; ++kc)
        af[kc] = *(const bf16x8*)&s_cat[mt * 16 + l15][kc * 32 + quad * 8];
      #pragma unroll
      for (int nt = 0; nt < 4; ++nt) {
        const int n = wave * 64 + nt * 16 + l15;
        const float bb = b_ip1[n];
        f32x4 acc = {bb, bb, bb, bb};
        #pragma unroll
        for (int kc = 0; kc < 3; ++kc)
          acc = __builtin_amdgcn_mfma_f32_16x16x32_bf16(af[kc], bfr[nt][kc], acc, 0, 0, 0);
        #pragma unroll
        for (int r = 0; r < 4; ++r) {
          int m = mt * 16 + quad * 4 + r;
          u.h[m][n] = (__bf16)fmaxf(acc[r], 0.f);
        }
      }
    }
  }
  __syncthreads();

  // ---- ip2 MFMA: [64,256] @ [256,128] -> T (fp32) ----
  {
    bf16x8 bfr[2][8];                     // wave owns cols wave*32..+31
    #pragma unroll
    for (int nt = 0; nt < 2; ++nt) {
      const int n = wave * 32 + nt * 16 + l15;
      #pragma unroll
      for (int kc = 0; kc < 8; ++kc)
        #pragma unroll
        for (int j = 0; j < 8; ++j) {
          int k = kc * 32 + quad * 8 + j;
          bfr[nt][kc][j] = (__bf16)w_ip2[k * OD + n];
        }
    }
    #pragma unroll
    for (int mt = 0; mt < 4; ++mt) {
      bf16x8 af[8];
      #pragma unroll
      for (int kc = 0; kc < 8; ++kc)
        af[kc] = *(const bf16x8*)&u.h[mt * 16 + l15][kc * 32 + quad * 8];
      #pragma unroll
      for (int nt = 0; nt < 2; ++nt) {
        const int n = wave * 32 + nt * 16 + l15;
        const float bb = b_ip2[n];
        f32x4 acc = {bb, bb, bb, bb};
        #pragma unroll
        for (int kc = 0; kc < 8; ++kc)
          acc = __builtin_amdgcn_mfma_f32_16x16x32_bf16(af[kc], bfr[nt][kc], acc, 0, 0, 0);
        #pragma unroll
        for (int r = 0; r < 4; ++r) {
          int m = mt * 16 + quad * 4 + r;
          int movie = blk * MB + m;
          if (movie < P) T[(long)movie * OD + n] = acc[r];
        }
      }
    }
  }
}

// ---------------------------------------------------------------------------
// Kernel 2: per-user pooling + user MLP + final dot. One block per user.
// Pooling gathers fully unrolled (ILP), genome pool parallelized.
// ---------------------------------------------------------------------------
__global__ __launch_bounds__(256) void user_kernel(
    const float* __restrict__ ugc, const int* __restrict__ hist,
    const float* __restrict__ ratings, const int* __restrict__ tstamps,
    const int* __restrict__ target, const float* __restrict__ ts_tab,
    const float* __restrict__ w_ugenre, const float* __restrict__ b_ugenre,
    const float* __restrict__ w_ts, const float* __restrict__ b_ts,
    const float* __restrict__ w_up1, const float* __restrict__ b_up1,
    const float* __restrict__ w_up2, const float* __restrict__ b_up2,
    const float* __restrict__ T, const float* __restrict__ GT,
    float* __restrict__ out)
{
  __shared__ float s_w[64];
  __shared__ int   s_ids[64];
  __shared__ float s_part[2][OD];
  __shared__ float s_gp[8][EGT];
  __shared__ float s_cat[OD + EGT + EUG + ETS];   // 180
  __shared__ float s_h[PHID];
  __shared__ float s_inv;
  __shared__ float s_red[2];

  const int b = blockIdx.x, t = threadIdx.x;

  if (t < 64) {
    int id = PAD; float w = 0.f;
    if (t < NH) {
      id = hist[b * NH + t];
      float r = ratings[b * NH + t];
      w = (id != PAD) ? r : 0.f;
    }
    s_ids[t] = id; s_w[t] = w;
    float s = fabsf(w);
    #pragma unroll
    for (int off = 32; off; off >>= 1) s += __shfl_xor(s, off, 64);
    if (t == 0) s_inv = 1.f / fmaxf(s, 1e-6f);
  }
  __syncthreads();
  const float inv = s_inv;

  // item pool: 2 partials per column, 25 independent gathers each
  {
    const int c = t & (OD - 1), part = t >> 7;
    float acc = 0.f;
    #pragma unroll
    for (int i = 0; i < 25; ++i) {
      const int h = part * 25 + i;
      acc = fmaf(s_w[h], T[(long)s_ids[h] * OD + c], acc);
    }
    s_part[part][c] = acc;
  }
  __syncthreads();
  if (t < OD) {
    s_cat[t] = (s_part[0][t] + s_part[1][t]) * inv;
  } else {
    const int uu = t - 128, col = uu & 15, part = uu >> 4;  // 8 parts x 7 h
    float acc = 0.f;
    #pragma unroll
    for (int i = 0; i < 7; ++i) {
      const int h = part * 7 + i;
      if (h < NH) acc = fmaf(s_w[h], GT[(long)s_ids[h] * EGT + col], acc);
    }
    s_gp[part][col] = acc;
  }
  __syncthreads();
  if (t < EGT) {
    float acc = 0.f;
    #pragma unroll
    for (int p = 0; p < 8; ++p) acc += s_gp[p][t];
    s_cat[OD + t] = acc * inv;
  } else if (t >= 32 && t < 32 + EUG) {
    const int j = t - 32;
    float a = b_ugenre[j];
    #pragma unroll
    for (int k = 0; k < NGENRES; ++k)
      a = fmaf(ugc[b * NGENRES + k], w_ugenre[k * EUG + j], a);
    s_cat[OD + EGT + j] = tanhf(a);
  } else if (t >= 64 && t < 64 + ETS) {
    const int j = t - 64;
    const int ts = tstamps[b];
    float a = b_ts[j];
    #pragma unroll
    for (int k = 0; k < ETS; ++k)
      a = fmaf(ts_tab[ts * ETS + k], w_ts[k * ETS + j], a);
    s_cat[OD + EGT + EUG + j] = tanhf(a);
  }
  __syncthreads();

  // up1: (180) @ (180,256) + relu; one hidden col per thread, coalesced w reads
  {
    float acc = b_up1[t];
    #pragma unroll 6
    for (int k = 0; k < OD + EGT + EUG + ETS; ++k)
      acc = fmaf(s_cat[k], w_up1[k * PHID + t], acc);
    s_h[t] = fmaxf(acc, 0.f);
  }
  __syncthreads();

  // up2: (256) @ (256,128), dot with T[target]
  if (t < OD) {
    float acc = b_up2[t];
    #pragma unroll 8
    for (int k = 0; k < PHID; ++k)
      acc = fmaf(s_h[k], w_up2[k * OD + t], acc);
    float prod = acc * T[(long)target[b] * OD + t];
    #pragma unroll
    for (int off = 32; off; off >>= 1) prod += __shfl_down(prod, off, 64);
    if ((t & 63) == 0) s_red[t >> 6] = prod;
  }
  __syncthreads();
  if (t == 0) out[b] = s_red[0] + s_red[1];
}

// ---------------------------------------------------------------------------
extern "C" void kernel_launch(void* const* d_in, const int* in_sizes, int n_in,
                              void* d_out, int out_size, void* d_ws, size_t ws_size,
                              hipStream_t stream) {
  const float* ugc      = (const float*)d_in[0];
  const int*   hist     = (const int*)  d_in[1];
  const float* ratings  = (const float*)d_in[2];
  const int*   tstamps  = (const int*)  d_in[3];
  const int*   target   = (const int*)  d_in[4];
  const float* genome   = (const float*)d_in[5];
  const float* genrec   = (const float*)d_in[6];
  const float* tagc     = (const float*)d_in[7];
  const int*   yearc    = (const int*)  d_in[8];
  const float* item_emb = (const float*)d_in[9];
  const float* year_tab = (const float*)d_in[10];
  const float* ts_tab   = (const float*)d_in[11];
  const float* w_item   = (const float*)d_in[12];
  const float* b_item   = (const float*)d_in[13];
  const float* w_genre  = (const float*)d_in[14];
  const float* b_genre  = (const float*)d_in[15];
  const float* w_tag    = (const float*)d_in[16];
  const float* b_tag    = (const float*)d_in[17];
  const float* w_genome = (const float*)d_in[18];
  const float* b_genome = (const float*)d_in[19];
  const float* w_year   = (const float*)d_in[20];
  const float* b_year   = (const float*)d_in[21];
  const float* w_ugenre = (const float*)d_in[22];
  const float* b_ugenre = (const float*)d_in[23];
  const float* w_ts     = (const float*)d_in[24];
  const float* b_ts     = (const float*)d_in[25];
  const float* w_up1    = (const float*)d_in[26];
  const float* b_up1    = (const float*)d_in[27];
  const float* w_up2    = (const float*)d_in[28];
  const float* b_up2    = (const float*)d_in[29];
  const float* w_ip1    = (const float*)d_in[30];
  const float* b_ip1    = (const float*)d_in[31];
  const float* w_ip2    = (const float*)d_in[32];
  const float* b_ip2    = (const float*)d_in[33];

  float* T  = (float*)d_ws;                                           // P*128 f32
  float* GT = (float*)((char*)d_ws + (size_t)P * OD * sizeof(float)); // P*16 f32

  dim3 blk(256);
  dim3 g1((P + MB - 1) / MB);
  movie_tower_kernel<<<g1, blk, 0, stream>>>(
      genome, genrec, tagc, yearc, item_emb, year_tab,
      w_item, b_item, w_genre, b_genre, w_tag, b_tag, w_genome, b_genome,
      w_year, b_year, w_ip1, b_ip1, w_ip2, b_ip2, T, GT);

  user_kernel<<<dim3(NB), blk, 0, stream>>>(
      ugc, hist, ratings, tstamps, target, ts_tab,
      w_ugenre, b_ugenre, w_ts, b_ts, w_up1, b_up1, w_up2, b_up2,
      T, GT, (float*)d_out);
}

// Round 4
// 368.663 us; speedup vs baseline: 1.5742x; 1.0302x over previous
//
#include <hip/hip_runtime.h>
#include <hip/hip_bf16.h>

typedef __bf16 bf16x8 __attribute__((ext_vector_type(8)));
typedef float  f32x4  __attribute__((ext_vector_type(4)));

namespace {
constexpr int P       = 20001;   // MOVIES + 1 (padding row)
constexpr int NGENRES = 20;
constexpr int NTAGS   = 1000;
constexpr int NGTAGS  = 1128;
constexpr int NB      = 1024;
constexpr int NH      = 50;
constexpr int PHID    = 256;
constexpr int OD      = 128;
constexpr int EG = 8, ET = 16, EGT = 16, EM = 32, EY = 8, EUG = 32, ETS = 4;
constexpr int PAD  = 20000;
constexpr int MB   = 32;     // movies per block (626 blocks)
constexpr int SBK  = 1176;   // sbt LDS stride (bf16): 16B-aligned rows, cap 1152
constexpr int SC   = 104;    // s_cat stride (96 used: 80 + 16 zero pad)
constexpr int SH   = 264;    // hidden stride (256 used)
constexpr int CATD = 80;
constexpr int UC   = 192;    // user-cat padded width (180 + 12 zeros)
constexpr int UCS  = 200;    // K3 LDS stride for Ucat tile
}

// Streaming 16x16 tile GEMM-slice: A rows direct global->reg (fp32->bf16),
// B from LDS (pre-staged, zero-padded past Kd). Wave handles chunks
// c = wsub, wsub+2, ... < nchunk (2-way K-split). Tail A loads are clamped to
// stay in-bounds (Kd is 8-aligned so no straddle); B rows >= Kd are zero so
// clamped-garbage A contributes nothing.
static __device__ __forceinline__ f32x4 stream_tile(
    const float* __restrict__ ctx, long rowbase, int Kd, int nchunk,
    const __bf16 (*__restrict__ sbt)[SBK], int wsub, int l15, int quad)
{
  f32x4 acc = {0.f, 0.f, 0.f, 0.f};
  const int kq = quad * 8;
  #pragma unroll 2
  for (int c = wsub; c < nchunk; c += 2) {
    const int k0 = c * 64 + kq;
    {
      int ka = min(k0, Kd - 4), kb = min(k0 + 4, Kd - 4);
      float4 va = *(const float4*)(ctx + rowbase + ka);
      float4 vb = *(const float4*)(ctx + rowbase + kb);
      bf16x8 af = {(__bf16)va.x, (__bf16)va.y, (__bf16)va.z, (__bf16)va.w,
                   (__bf16)vb.x, (__bf16)vb.y, (__bf16)vb.z, (__bf16)vb.w};
      bf16x8 bfr = *(const bf16x8*)&sbt[l15][k0];
      acc = __builtin_amdgcn_mfma_f32_16x16x32_bf16(af, bfr, acc, 0, 0, 0);
    }
    {
      const int k1 = k0 + 32;
      int ka = min(k1, Kd - 4), kb = min(k1 + 4, Kd - 4);
      float4 va = *(const float4*)(ctx + rowbase + ka);
      float4 vb = *(const float4*)(ctx + rowbase + kb);
      bf16x8 af = {(__bf16)va.x, (__bf16)va.y, (__bf16)va.z, (__bf16)va.w,
                   (__bf16)vb.x, (__bf16)vb.y, (__bf16)vb.z, (__bf16)vb.w};
      bf16x8 bfr = *(const bf16x8*)&sbt[l15][k1];
      acc = __builtin_amdgcn_mfma_f32_16x16x32_bf16(af, bfr, acc, 0, 0, 0);
    }
  }
  return acc;
}

// ---------------------------------------------------------------------------
// Kernel 1: item_tower for ALL movies. 626 blocks x 256 thr, 32 movies/block.
// 2 movie-tiles of 16; 2 waves per tile split K; no barriers inside K-loops.
// ---------------------------------------------------------------------------
__global__ __launch_bounds__(256) void movie_tower_kernel(
    const float* __restrict__ genome_ctx, const float* __restrict__ genre_ctx,
    const float* __restrict__ tag_ctx,    const int*   __restrict__ year_ctx,
    const float* __restrict__ item_emb,   const float* __restrict__ year_tab,
    const float* __restrict__ w_item,  const float* __restrict__ b_item,
    const float* __restrict__ w_genre, const float* __restrict__ b_genre,
    const float* __restrict__ w_tag,   const float* __restrict__ b_tag,
    const float* __restrict__ w_genome,const float* __restrict__ b_genome,
    const float* __restrict__ w_year,  const float* __restrict__ b_year,
    const float* __restrict__ w_ip1,   const float* __restrict__ b_ip1,
    const float* __restrict__ w_ip2,   const float* __restrict__ b_ip2,
    float* __restrict__ T, float* __restrict__ GT)
{
  union ShU { __bf16 sbt[16][SBK]; __bf16 h[MB][SH]; };  // 37.6 KB / 16.9 KB
  __shared__ __align__(16) ShU u;
  __shared__ __align__(16) __bf16 s_cat[MB][SC];         // 6.7 KB
  __shared__ f32x4 s_redT[2][64];                        // 2 KB
  __shared__ f32x4 s_redG[2][64];                        // 2 KB
  __shared__ int s_ids[MB];

  const int t = threadIdx.x, blk = blockIdx.x;
  const int wave = t >> 6, lane = t & 63, l15 = lane & 15, quad = lane >> 4;
  const int tile = wave >> 1, wsub = wave & 1;

  if (t < MB) {
    int mv = blk * MB + t;
    s_ids[t] = mv < P ? mv : P - 1;
  }

  // ---- stage tag B (transposed, bf16, zero-pad k>=1000) ----
  #pragma unroll
  for (int it = 0; it < 16; ++it) {
    int idx = it * 256 + t;
    int k = idx >> 2, ng = (idx & 3) * 4;
    float4 v = make_float4(0.f, 0.f, 0.f, 0.f);
    if (k < NTAGS) v = *(const float4*)(w_tag + k * ET + ng);
    u.sbt[ng + 0][k] = (__bf16)v.x; u.sbt[ng + 1][k] = (__bf16)v.y;
    u.sbt[ng + 2][k] = (__bf16)v.z; u.sbt[ng + 3][k] = (__bf16)v.w;
  }
  __syncthreads();

  const int myrow = s_ids[tile * 16 + l15];
  f32x4 accT = stream_tile(tag_ctx, (long)myrow * NTAGS, NTAGS, 16,
                           u.sbt, wsub, l15, quad);
  __syncthreads();

  // ---- stage genome B (zero-pad k>=1128) ----
  #pragma unroll
  for (int it = 0; it < 18; ++it) {
    int idx = it * 256 + t;
    int k = idx >> 2, ng = (idx & 3) * 4;
    float4 v = make_float4(0.f, 0.f, 0.f, 0.f);
    if (k < NGTAGS) v = *(const float4*)(w_genome + k * EGT + ng);
    u.sbt[ng + 0][k] = (__bf16)v.x; u.sbt[ng + 1][k] = (__bf16)v.y;
    u.sbt[ng + 2][k] = (__bf16)v.z; u.sbt[ng + 3][k] = (__bf16)v.w;
  }
  __syncthreads();
  f32x4 accG = stream_tile(genome_ctx, (long)myrow * NGTAGS, NGTAGS, 18,
                           u.sbt, wsub, l15, quad);

  // ---- cross-wave K reduction + tag/genome epilogue ----
  if (wsub == 1) { s_redT[tile][lane] = accT; s_redG[tile][lane] = accG; }
  __syncthreads();
  if (wsub == 0) {
    accT += s_redT[tile][lane];
    accG += s_redG[tile][lane];
    const float bt = b_tag[l15], bg = b_genome[l15];
    #pragma unroll
    for (int r = 0; r < 4; ++r) {
      int m = tile * 16 + quad * 4 + r;
      float vT = tanhf(accT[r] + bt);
      float vG = tanhf(accG[r] + bg);
      s_cat[m][EG + l15]      = (__bf16)vT;
      s_cat[m][EG + ET + l15] = (__bf16)vG;
      int movie = blk * MB + m;
      if (movie < P) GT[movie * EGT + l15] = vG;
    }
  }

  // ---- small towers (all threads; disjoint s_cat columns) ----
  {
    const int m = t >> 3, j = t & 7;
    const long rb = (long)s_ids[m];
    const float* rg = genre_ctx + rb * NGENRES;
    float a = b_genre[j];
    #pragma unroll
    for (int k = 0; k < NGENRES; ++k) a = fmaf(rg[k], w_genre[k * EG + j], a);
    s_cat[m][j] = (__bf16)tanhf(a);

    const int yr = year_ctx[rb];
    float ay = b_year[j];
    #pragma unroll
    for (int k = 0; k < EY; ++k)
      ay = fmaf(year_tab[yr * EY + k], w_year[k * EY + j], ay);
    s_cat[m][72 + j] = (__bf16)tanhf(ay);   // 72 = EG+ET+EGT+EM

    const int j0 = (t & 7) * 4;
    const float* e = item_emb + rb * EM;
    float ai[4];
    #pragma unroll
    for (int i = 0; i < 4; ++i) ai[i] = b_item[j0 + i];
    #pragma unroll 8
    for (int k = 0; k < EM; ++k) {
      float ev = e[k];
      #pragma unroll
      for (int i = 0; i < 4; ++i) ai[i] = fmaf(ev, w_item[k * EM + j0 + i], ai[i]);
    }
    #pragma unroll
    for (int i = 0; i < 4; ++i)
      s_cat[m][40 + j0 + i] = (__bf16)tanhf(ai[i]);  // 40 = EG+ET+EGT
  }
  #pragma unroll
  for (int i = 0; i < 2; ++i) {          // zero K-pad cols 80..95
    int idx = t * 2 + i;
    s_cat[idx >> 4][80 + (idx & 15)] = (__bf16)0.f;
  }
  __syncthreads();

  // ---- ip1 MFMA: [32,96]@[96,256] -> relu -> u.h. Wave = (m-tile, n-half) --
  {
    const int mt = tile, nh = wsub;
    bf16x8 a1[3];
    #pragma unroll
    for (int kc = 0; kc < 3; ++kc)
      a1[kc] = *(const bf16x8*)&s_cat[mt * 16 + l15][kc * 32 + quad * 8];
    #pragma unroll 2
    for (int nt = 0; nt < 8; ++nt) {
      const int n = nh * 128 + nt * 16 + l15;
      bf16x8 bfr[3];
      #pragma unroll
      for (int kc = 0; kc < 3; ++kc)
        #pragma unroll
        for (int j = 0; j < 8; ++j) {
          int kk = kc * 32 + quad * 8 + j;
          bfr[kc][j] = (__bf16)(kk < CATD ? w_ip1[kk * PHID + n] : 0.f);
        }
      const float bb = b_ip1[n];
      f32x4 acc = {bb, bb, bb, bb};
      #pragma unroll
      for (int kc = 0; kc < 3; ++kc)
        acc = __builtin_amdgcn_mfma_f32_16x16x32_bf16(a1[kc], bfr[kc], acc, 0, 0, 0);
      #pragma unroll
      for (int r = 0; r < 4; ++r)
        u.h[mt * 16 + quad * 4 + r][n] = (__bf16)fmaxf(acc[r], 0.f);
    }
  }
  __syncthreads();

  // ---- ip2 MFMA: [32,256]@[256,128] -> T. Wave covers 64 cols (nt=0..3) ----
  {
    const int mt = tile, nh = wsub;
    bf16x8 a2[8];
    #pragma unroll
    for (int kc = 0; kc < 8; ++kc)
      a2[kc] = *(const bf16x8*)&u.h[mt * 16 + l15][kc * 32 + quad * 8];
    #pragma unroll 2
    for (int nt = 0; nt < 4; ++nt) {           // BUGFIX r3: was nt < 2
      const int n = nh * 64 + nt * 16 + l15;
      bf16x8 bfr[8];
      #pragma unroll
      for (int kc = 0; kc < 8; ++kc)
        #pragma unroll
        for (int j = 0; j < 8; ++j)
          bfr[kc][j] = (__bf16)w_ip2[(kc * 32 + quad * 8 + j) * OD + n];
      const float bb = b_ip2[n];
      f32x4 acc = {bb, bb, bb, bb};
      #pragma unroll
      for (int kc = 0; kc < 8; ++kc)
        acc = __builtin_amdgcn_mfma_f32_16x16x32_bf16(a2[kc], bfr[kc], acc, 0, 0, 0);
      #pragma unroll
      for (int r = 0; r < 4; ++r) {
        int movie = blk * MB + mt * 16 + quad * 4 + r;
        if (movie < P) T[(long)movie * OD + n] = acc[r];
      }
    }
  }
}

// ---------------------------------------------------------------------------
// Kernel 2: per-user pooling -> Ucat[1024][192] bf16 (180 real + 12 zeros).
// ---------------------------------------------------------------------------
__global__ __launch_bounds__(256) void user_pool_kernel(
    const float* __restrict__ ugc, const int* __restrict__ hist,
    const float* __restrict__ ratings, const int* __restrict__ tstamps,
    const float* __restrict__ ts_tab,
    const float* __restrict__ w_ugenre, const float* __restrict__ b_ugenre,
    const float* __restrict__ w_ts, const float* __restrict__ b_ts,
    const float* __restrict__ T, const float* __restrict__ GT,
    __bf16* __restrict__ Ucat)
{
  __shared__ float s_w[64];
  __shared__ int   s_ids[64];
  __shared__ float s_part[2][OD];
  __shared__ float s_gp[8][EGT];
  __shared__ float s_inv;

  const int b = blockIdx.x, t = threadIdx.x;

  if (t < 64) {
    int id = PAD; float w = 0.f;
    if (t < NH) {
      id = hist[b * NH + t];
      float r = ratings[b * NH + t];
      w = (id != PAD) ? r : 0.f;
    }
    s_ids[t] = id; s_w[t] = w;
    float s = fabsf(w);
    #pragma unroll
    for (int off = 32; off; off >>= 1) s += __shfl_xor(s, off, 64);
    if (t == 0) s_inv = 1.f / fmaxf(s, 1e-6f);
  }
  __syncthreads();
  const float inv = s_inv;

  {  // item pool partials: 2 x 25 gathers per column
    const int c = t & (OD - 1), part = t >> 7;
    float acc = 0.f;
    #pragma unroll
    for (int i = 0; i < 25; ++i) {
      const int h = part * 25 + i;
      acc = fmaf(s_w[h], T[(long)s_ids[h] * OD + c], acc);
    }
    s_part[part][c] = acc;
  }
  __syncthreads();
  if (t < OD) {
    Ucat[(long)b * UC + t] = (__bf16)((s_part[0][t] + s_part[1][t]) * inv);
  } else {
    const int uu = t - 128, col = uu & 15, part = uu >> 4;  // 8 parts x 7 h
    float acc = 0.f;
    #pragma unroll
    for (int i = 0; i < 7; ++i) {
      const int h = part * 7 + i;
      if (h < NH) acc = fmaf(s_w[h], GT[(long)s_ids[h] * EGT + col], acc);
    }
    s_gp[part][col] = acc;
  }
  __syncthreads();
  if (t < EGT) {
    float acc = 0.f;
    #pragma unroll
    for (int p = 0; p < 8; ++p) acc += s_gp[p][t];
    Ucat[(long)b * UC + OD + t] = (__bf16)(acc * inv);
  } else if (t >= 32 && t < 64) {
    const int j = t - 32;
    float a = b_ugenre[j];
    #pragma unroll
    for (int k = 0; k < NGENRES; ++k)
      a = fmaf(ugc[b * NGENRES + k], w_ugenre[k * EUG + j], a);
    Ucat[(long)b * UC + 144 + j] = (__bf16)tanhf(a);     // 128+16
  } else if (t >= 64 && t < 64 + ETS) {
    const int j = t - 64;
    const int ts = tstamps[b];
    float a = b_ts[j];
    #pragma unroll
    for (int k = 0; k < ETS; ++k)
      a = fmaf(ts_tab[ts * ETS + k], w_ts[k * ETS + j], a);
    Ucat[(long)b * UC + 176 + j] = (__bf16)tanhf(a);     // 128+16+32
  } else if (t >= 68 && t < 80) {
    Ucat[(long)b * UC + 180 + (t - 68)] = (__bf16)0.f;   // zero pad
  }
}

// ---------------------------------------------------------------------------
// Kernel 3: user MLP via MFMA + final dot. 32 blocks x 32 users.
// ---------------------------------------------------------------------------
__global__ __launch_bounds__(256) void user_mlp_kernel(
    const int* __restrict__ target,
    const float* __restrict__ w_up1, const float* __restrict__ b_up1,
    const float* __restrict__ w_up2, const float* __restrict__ b_up2,
    const __bf16* __restrict__ Ucat, const float* __restrict__ T,
    float* __restrict__ out)
{
  __shared__ __align__(16) __bf16 s_u[32][UCS];   // 12.8 KB
  __shared__ __align__(16) __bf16 s_h[32][SH];    // 16.9 KB
  __shared__ __align__(16) float  s_e[32][132];   // 16.9 KB

  const int t = threadIdx.x, blk = blockIdx.x;
  const int wave = t >> 6, lane = t & 63, l15 = lane & 15, quad = lane >> 4;
  const int u0 = blk * 32;

  {  // stage Ucat tile: thread = (user t>>3, 24-col segment t&7)
    const int uu = t >> 3, seg = t & 7;
    const __bf16* src = Ucat + (long)(u0 + uu) * UC + seg * 24;
    #pragma unroll
    for (int i = 0; i < 3; ++i)
      *(bf16x8*)&s_u[uu][seg * 24 + i * 8] = *(const bf16x8*)(src + i * 8);
  }
  __syncthreads();

  // ---- up1: [32,192]@[192,256] -> relu -> s_h ----
  #pragma unroll 2
  for (int nt = 0; nt < 4; ++nt) {
    const int n = wave * 64 + nt * 16 + l15;
    bf16x8 bfr[6];
    #pragma unroll
    for (int kc = 0; kc < 6; ++kc)
      #pragma unroll
      for (int j = 0; j < 8; ++j) {
        int kk = kc * 32 + quad * 8 + j;
        bfr[kc][j] = (__bf16)(kk < 180 ? w_up1[kk * PHID + n] : 0.f);
      }
    const float bb = b_up1[n];
    #pragma unroll
    for (int mt = 0; mt < 2; ++mt) {
      f32x4 acc = {bb, bb, bb, bb};
      #pragma unroll
      for (int kc = 0; kc < 6; ++kc) {
        bf16x8 a = *(const bf16x8*)&s_u[mt * 16 + l15][kc * 32 + quad * 8];
        acc = __builtin_amdgcn_mfma_f32_16x16x32_bf16(a, bfr[kc], acc, 0, 0, 0);
      }
      #pragma unroll
      for (int r = 0; r < 4; ++r)
        s_h[mt * 16 + quad * 4 + r][n] = (__bf16)fmaxf(acc[r], 0.f);
    }
  }
  __syncthreads();

  // ---- up2: [32,256]@[256,128] -> s_e (fp32) ----
  #pragma unroll
  for (int nt = 0; nt < 2; ++nt) {
    const int n = wave * 32 + nt * 16 + l15;
    bf16x8 bfr[8];
    #pragma unroll
    for (int kc = 0; kc < 8; ++kc)
      #pragma unroll
      for (int j = 0; j < 8; ++j)
        bfr[kc][j] = (__bf16)w_up2[(kc * 32 + quad * 8 + j) * OD + n];
    const float bb = b_up2[n];
    #pragma unroll
    for (int mt = 0; mt < 2; ++mt) {
      f32x4 acc = {bb, bb, bb, bb};
      #pragma unroll
      for (int kc = 0; kc < 8; ++kc) {
        bf16x8 a = *(const bf16x8*)&s_h[mt * 16 + l15][kc * 32 + quad * 8];
        acc = __builtin_amdgcn_mfma_f32_16x16x32_bf16(a, bfr[kc], acc, 0, 0, 0);
      }
      #pragma unroll
      for (int r = 0; r < 4; ++r)
        s_e[mt * 16 + quad * 4 + r][n] = acc[r];
    }
  }
  __syncthreads();

  // ---- dot(user, T[target]): 8 threads per user, 16 cols each ----
  {
    const int uu = t >> 3, q = t & 7;
    const int tgt = target[u0 + uu];
    const float* trow = T + (long)tgt * OD + q * 16;
    float s = 0.f;
    #pragma unroll
    for (int i = 0; i < 4; ++i) {
      float4 v = *(const float4*)(trow + i * 4);
      f32x4 e = *(const f32x4*)&s_e[uu][q * 16 + i * 4];
      s += v.x * e[0] + v.y * e[1] + v.z * e[2] + v.w * e[3];
    }
    s += __shfl_down(s, 1, 64);
    s += __shfl_down(s, 2, 64);
    s += __shfl_down(s, 4, 64);
    if (q == 0) out[u0 + uu] = s;
  }
}

// ---------------------------------------------------------------------------
extern "C" void kernel_launch(void* const* d_in, const int* in_sizes, int n_in,
                              void* d_out, int out_size, void* d_ws, size_t ws_size,
                              hipStream_t stream) {
  const float* ugc      = (const float*)d_in[0];
  const int*   hist     = (const int*)  d_in[1];
  const float* ratings  = (const float*)d_in[2];
  const int*   tstamps  = (const int*)  d_in[3];
  const int*   target   = (const int*)  d_in[4];
  const float* genome   = (const float*)d_in[5];
  const float* genrec   = (const float*)d_in[6];
  const float* tagc     = (const float*)d_in[7];
  const int*   yearc    = (const int*)  d_in[8];
  const float* item_emb = (const float*)d_in[9];
  const float* year_tab = (const float*)d_in[10];
  const float* ts_tab   = (const float*)d_in[11];
  const float* w_item   = (const float*)d_in[12];
  const float* b_item   = (const float*)d_in[13];
  const float* w_genre  = (const float*)d_in[14];
  const float* b_genre  = (const float*)d_in[15];
  const float* w_tag    = (const float*)d_in[16];
  const float* b_tag    = (const float*)d_in[17];
  const float* w_genome = (const float*)d_in[18];
  const float* b_genome = (const float*)d_in[19];
  const float* w_year   = (const float*)d_in[20];
  const float* b_year   = (const float*)d_in[21];
  const float* w_ugenre = (const float*)d_in[22];
  const float* b_ugenre = (const float*)d_in[23];
  const float* w_ts     = (const float*)d_in[24];
  const float* b_ts     = (const float*)d_in[25];
  const float* w_up1    = (const float*)d_in[26];
  const float* b_up1    = (const float*)d_in[27];
  const float* w_up2    = (const float*)d_in[28];
  const float* b_up2    = (const float*)d_in[29];
  const float* w_ip1    = (const float*)d_in[30];
  const float* b_ip1    = (const float*)d_in[31];
  const float* w_ip2    = (const float*)d_in[32];
  const float* b_ip2    = (const float*)d_in[33];

  float*  T    = (float*)d_ws;                                   // P*128 f32
  float*  GT   = (float*)((char*)d_ws + (size_t)P * OD * 4);     // P*16 f32
  __bf16* Ucat = (__bf16*)((char*)d_ws + (size_t)P * OD * 4 + (size_t)P * EGT * 4);

  dim3 blk(256);
  movie_tower_kernel<<<dim3((P + MB - 1) / MB), blk, 0, stream>>>(
      genome, genrec, tagc, yearc, item_emb, year_tab,
      w_item, b_item, w_genre, b_genre, w_tag, b_tag, w_genome, b_genome,
      w_year, b_year, w_ip1, b_ip1, w_ip2, b_ip2, T, GT);

  user_pool_kernel<<<dim3(NB), blk, 0, stream>>>(
      ugc, hist, ratings, tstamps, ts_tab,
      w_ugenre, b_ugenre, w_ts, b_ts, T, GT, Ucat);

  user_mlp_kernel<<<dim3(NB / 32), blk, 0, stream>>>(
      target, w_up1, b_up1, w_up2, b_up2, Ucat, T, (float*)d_out);
}

// Round 5
// 286.082 us; speedup vs baseline: 2.0286x; 1.2887x over previous
//
#include <hip/hip_runtime.h>
#include <hip/hip_bf16.h>

typedef __bf16 bf16x8 __attribute__((ext_vector_type(8)));
typedef __bf16 bf16x4 __attribute__((ext_vector_type(4)));
typedef float  f32x4  __attribute__((ext_vector_type(4)));

namespace {
constexpr int P       = 20001;   // MOVIES + 1 (padding row)
constexpr int NT_TILE = 1251;    // ceil(P/16) -> covers movies 0..20015
constexpr int PROWS   = NT_TILE * 16;  // 20016 padded rows for T/GT
constexpr int NGENRES = 20;
constexpr int NTAGS   = 1000;
constexpr int NGTAGS  = 1128;
constexpr int NB      = 1024;
constexpr int NH      = 50;
constexpr int PHID    = 256;
constexpr int OD      = 128;
constexpr int EG = 8, ET = 16, EGT = 16, EM = 32, EY = 8, EUG = 32, ETS = 4;
constexpr int PAD  = 20000;
constexpr int SAW  = 1160;   // s_a stride bf16 (1152 used for genome, 16B-mult)
constexpr int SC   = 104;    // s_cat stride bf16 (96 used)
constexpr int SH   = 264;    // hidden stride bf16 (256 used)
constexpr int UC   = 192;    // user-cat padded width (180 + 12 zeros)
constexpr int UCS  = 200;    // mlp LDS stride for Ucat tile
// fragment-table chunk counts (chunks of K=32 -> one [64][8] bf16 frag = 1KB)
constexpr int KC_TAG = 32, KC_GEN = 36;
constexpr int KC_IP1 = 3,  NT_IP1 = 16;   // K=96(80 real), N=256
constexpr int KC_IP2 = 8,  NT_IP2 = 8;    // K=256, N=128
constexpr int KC_UP1 = 6,  NT_UP1 = 16;   // K=192(180 real), N=256
constexpr int KC_UP2 = 8,  NT_UP2 = 8;    // K=256, N=128
}

static __device__ __forceinline__ f32x4 mfma16(bf16x8 a, bf16x8 b, f32x4 c) {
  return __builtin_amdgcn_mfma_f32_16x16x32_bf16(a, b, c, 0, 0, 0);
}

// ---------------------------------------------------------------------------
// Setup: pre-swizzle all MFMA B-operands into fragment layout:
// frag(kc, nt)[lane][j] = W[kc*32 + (lane>>4)*8 + j][nt*16 + (lane&15)] (bf16,
// zero past K). One block (512 thr) per fragment; 340 fragments total.
// ---------------------------------------------------------------------------
__global__ __launch_bounds__(512) void setup_wf_kernel(
    const float* __restrict__ w_tag, const float* __restrict__ w_genome,
    const float* __restrict__ w_ip1, const float* __restrict__ w_ip2,
    const float* __restrict__ w_up1, const float* __restrict__ w_up2,
    __bf16* __restrict__ Wtf, __bf16* __restrict__ Wgf,
    __bf16* __restrict__ Wip1f, __bf16* __restrict__ Wip2f,
    __bf16* __restrict__ Wup1f, __bf16* __restrict__ Wup2f)
{
  const int b = blockIdx.x, t = threadIdx.x;
  const int l = t >> 3, j = t & 7;
  const int krow = (l >> 4) * 8 + j, l15 = l & 15;
  const float* src; __bf16* dst; int K, N, kc, nt;
  if (b < 32)        { src = w_tag;    dst = Wtf   + (long)b * 512;       K = NTAGS;  N = 16;  kc = b;      nt = 0; }
  else if (b < 68)   { int i = b - 32;  src = w_genome; dst = Wgf   + (long)i * 512; K = NGTAGS; N = 16;  kc = i;      nt = 0; }
  else if (b < 116)  { int i = b - 68;  src = w_ip1;    dst = Wip1f + (long)i * 512; K = 80;     N = 256; kc = i / 16; nt = i % 16; }
  else if (b < 180)  { int i = b - 116; src = w_ip2;    dst = Wip2f + (long)i * 512; K = 256;    N = 128; kc = i / 8;  nt = i % 8; }
  else if (b < 276)  { int i = b - 180; src = w_up1;    dst = Wup1f + (long)i * 512; K = 180;    N = 256; kc = i / 16; nt = i % 16; }
  else               { int i = b - 276; src = w_up2;    dst = Wup2f + (long)i * 512; K = 256;    N = 128; kc = i / 8;  nt = i % 8; }
  const int k = kc * 32 + krow, n = nt * 16 + l15;
  float v = (k < K) ? src[(long)k * N + n] : 0.f;
  dst[t] = (__bf16)v;
}

// ---------------------------------------------------------------------------
// Tower: one block = one 16-movie tile. Coalesced row staging -> LDS bf16,
// K-split MFMA (4 waves), fused small towers + ip1 + ip2. Emits T, GT.
// ---------------------------------------------------------------------------
__global__ __launch_bounds__(256) void tower_kernel(
    const float* __restrict__ tag_ctx, const float* __restrict__ genome_ctx,
    const float* __restrict__ genre_ctx, const int* __restrict__ year_ctx,
    const float* __restrict__ item_emb, const float* __restrict__ year_tab,
    const float* __restrict__ w_genre, const float* __restrict__ b_genre,
    const float* __restrict__ b_tag,   const float* __restrict__ b_genome,
    const float* __restrict__ w_item,  const float* __restrict__ b_item,
    const float* __restrict__ w_year,  const float* __restrict__ b_year,
    const float* __restrict__ b_ip1,   const float* __restrict__ b_ip2,
    const __bf16* __restrict__ Wtf,   const __bf16* __restrict__ Wgf,
    const __bf16* __restrict__ Wip1f, const __bf16* __restrict__ Wip2f,
    float* __restrict__ T, float* __restrict__ GT)
{
  union ShU { __bf16 a[16][SAW]; __bf16 h[16][SH]; };   // 37.1 KB / 8.4 KB
  __shared__ __align__(16) ShU u;
  __shared__ __align__(16) __bf16 s_cat[16][SC];        // 3.3 KB
  __shared__ __align__(16) f32x4  s_red[3][64];         // 3 KB

  const int t = threadIdx.x, tile = blockIdx.x;
  const int wave = t >> 6, lane = t & 63, l15 = lane & 15, quad = lane >> 4;
  const int r = t >> 4, c16 = t & 15;                   // staging coords
  const long rid = min(tile * 16 + r, P - 1);

  // ===== P0: stage tag rows (coalesced fp32 -> bf16 LDS) =====
  {
    const float* row = tag_ctx + rid * NTAGS;
    #pragma unroll
    for (int i = 0; i < 16; ++i) {
      int f = c16 + i * 16;                              // float4 index, 250 real
      if (f < 250) {
        float4 v = *(const float4*)(row + f * 4);
        bf16x4 b4 = {(__bf16)v.x, (__bf16)v.y, (__bf16)v.z, (__bf16)v.w};
        *(bf16x4*)&u.a[r][f * 4] = b4;
      }
    }
    if (c16 < 8) *(bf16x4*)&u.a[r][NTAGS + c16 * 4] = (bf16x4){(__bf16)0.f,(__bf16)0.f,(__bf16)0.f,(__bf16)0.f};
  }
  __syncthreads();

  // ===== P1: tag MFMA (K-split: wave w owns kc w*8..w*8+7 of 32) =====
  f32x4 accT = {0.f, 0.f, 0.f, 0.f};
  #pragma unroll
  for (int kc = 0; kc < 8; ++kc) {
    const int kcg = wave * 8 + kc;
    bf16x8 a  = *(const bf16x8*)&u.a[l15][kcg * 32 + quad * 8];
    bf16x8 bb = *(const bf16x8*)(Wtf + ((long)kcg * 64 + lane) * 8);
    accT = mfma16(a, bb, accT);
  }
  if (wave > 0) s_red[wave - 1][lane] = accT;
  __syncthreads();

  // ===== P2: stage genome rows; wave0 concurrently finishes tag epilogue ====
  {
    const float* row = genome_ctx + rid * NGTAGS;
    #pragma unroll
    for (int i = 0; i < 18; ++i) {
      int f = c16 + i * 16;                              // 282 real float4s
      if (f < 282) {
        float4 v = *(const float4*)(row + f * 4);
        bf16x4 b4 = {(__bf16)v.x, (__bf16)v.y, (__bf16)v.z, (__bf16)v.w};
        *(bf16x4*)&u.a[r][f * 4] = b4;
      }
    }
    if (c16 < 8) *(bf16x4*)&u.a[r][NGTAGS + c16 * 4] = (bf16x4){(__bf16)0.f,(__bf16)0.f,(__bf16)0.f,(__bf16)0.f};
  }
  if (wave == 0) {
    accT += s_red[0][lane]; accT += s_red[1][lane]; accT += s_red[2][lane];
    const float bt = b_tag[l15];
    #pragma unroll
    for (int r2 = 0; r2 < 4; ++r2)
      s_cat[quad * 4 + r2][EG + l15] = (__bf16)tanhf(accT[r2] + bt);
  }
  __syncthreads();

  // ===== P3: genome MFMA (wave w owns kc w*9..w*9+8 of 36) =====
  f32x4 accG = {0.f, 0.f, 0.f, 0.f};
  #pragma unroll
  for (int kc = 0; kc < 9; ++kc) {
    const int kcg = wave * 9 + kc;
    bf16x8 a  = *(const bf16x8*)&u.a[l15][kcg * 32 + quad * 8];
    bf16x8 bb = *(const bf16x8*)(Wgf + ((long)kcg * 64 + lane) * 8);
    accG = mfma16(a, bb, accG);
  }
  if (wave > 0) s_red[wave - 1][lane] = accG;
  __syncthreads();

  // ===== P4: genome epilogue (wave0) + small towers (all threads) =====
  if (wave == 0) {
    accG += s_red[0][lane]; accG += s_red[1][lane]; accG += s_red[2][lane];
    const float bg = b_genome[l15];
    #pragma unroll
    for (int r2 = 0; r2 < 4; ++r2) {
      int m = quad * 4 + r2;
      float v = tanhf(accG[r2] + bg);
      s_cat[m][EG + ET + l15] = (__bf16)v;
      GT[(long)(tile * 16 + m) * EGT + l15] = v;
    }
  }
  {
    // 16 threads per movie: m = t>>4, j = t&15
    const int m = r, j = c16;
    const long id = rid;
    if (j < 8) {   // genre tower (8 cols)
      const float* rg = genre_ctx + id * NGENRES;
      float a = b_genre[j];
      #pragma unroll
      for (int k = 0; k < NGENRES; ++k) a = fmaf(rg[k], w_genre[k * EG + j], a);
      s_cat[m][j] = (__bf16)tanhf(a);
      s_cat[m][80 + j] = (__bf16)0.f;          // zero K-pad 80..95
      s_cat[m][88 + j] = (__bf16)0.f;
    } else {       // year tower (8 cols)
      const int jj = j - 8;
      const int yr = year_ctx[id];
      float a = b_year[jj];
      #pragma unroll
      for (int k = 0; k < EY; ++k)
        a = fmaf(year_tab[yr * EY + k], w_year[k * EY + jj], a);
      s_cat[m][72 + jj] = (__bf16)tanhf(a);    // 72 = EG+ET+EGT+EM
    }
    // item tower: every thread 2 cols
    const float* e = item_emb + id * EM;
    float a0 = b_item[2 * j], a1 = b_item[2 * j + 1];
    #pragma unroll 8
    for (int k = 0; k < EM; ++k) {
      float ev = e[k];
      a0 = fmaf(ev, w_item[k * EM + 2 * j], a0);
      a1 = fmaf(ev, w_item[k * EM + 2 * j + 1], a1);
    }
    s_cat[m][40 + 2 * j]     = (__bf16)tanhf(a0);   // 40 = EG+ET+EGT
    s_cat[m][40 + 2 * j + 1] = (__bf16)tanhf(a1);
  }
  __syncthreads();

  // ===== P5: ip1 MFMA [16,96]@[96,256] -> relu -> u.h =====
  {
    bf16x8 af[KC_IP1];
    #pragma unroll
    for (int kc = 0; kc < KC_IP1; ++kc)
      af[kc] = *(const bf16x8*)&s_cat[l15][kc * 32 + quad * 8];
    #pragma unroll
    for (int nt = 0; nt < 4; ++nt) {
      const int n = wave * 64 + nt * 16 + l15;
      const float bb = b_ip1[n];
      f32x4 acc = {bb, bb, bb, bb};
      #pragma unroll
      for (int kc = 0; kc < KC_IP1; ++kc) {
        bf16x8 bfr = *(const bf16x8*)(Wip1f + ((long)(kc * NT_IP1 + wave * 4 + nt) * 64 + lane) * 8);
        acc = mfma16(af[kc], bfr, acc);
      }
      #pragma unroll
      for (int r2 = 0; r2 < 4; ++r2)
        u.h[quad * 4 + r2][n] = (__bf16)fmaxf(acc[r2], 0.f);
    }
  }
  __syncthreads();

  // ===== P6: ip2 MFMA [16,256]@[256,128] -> T =====
  {
    bf16x8 af[KC_IP2];
    #pragma unroll
    for (int kc = 0; kc < KC_IP2; ++kc)
      af[kc] = *(const bf16x8*)&u.h[l15][kc * 32 + quad * 8];
    #pragma unroll
    for (int nt = 0; nt < 2; ++nt) {
      const int n = wave * 32 + nt * 16 + l15;
      const float bb = b_ip2[n];
      f32x4 acc = {bb, bb, bb, bb};
      #pragma unroll
      for (int kc = 0; kc < KC_IP2; ++kc) {
        bf16x8 bfr = *(const bf16x8*)(Wip2f + ((long)(kc * NT_IP2 + wave * 2 + nt) * 64 + lane) * 8);
        acc = mfma16(af[kc], bfr, acc);
      }
      #pragma unroll
      for (int r2 = 0; r2 < 4; ++r2)
        T[(long)(tile * 16 + quad * 4 + r2) * OD + n] = acc[r2];
    }
  }
}

// ---------------------------------------------------------------------------
// Pool: per-user pooling -> Ucat[1024][192] bf16 (180 real + 12 zeros).
// ---------------------------------------------------------------------------
__global__ __launch_bounds__(256) void user_pool_kernel(
    const float* __restrict__ ugc, const int* __restrict__ hist,
    const float* __restrict__ ratings, const int* __restrict__ tstamps,
    const float* __restrict__ ts_tab,
    const float* __restrict__ w_ugenre, const float* __restrict__ b_ugenre,
    const float* __restrict__ w_ts, const float* __restrict__ b_ts,
    const float* __restrict__ T, const float* __restrict__ GT,
    __bf16* __restrict__ Ucat)
{
  __shared__ float s_w[64];
  __shared__ int   s_ids[64];
  __shared__ float s_part[2][OD];
  __shared__ float s_gp[8][EGT];
  __shared__ float s_inv;

  const int b = blockIdx.x, t = threadIdx.x;

  if (t < 64) {
    int id = PAD; float w = 0.f;
    if (t < NH) {
      id = hist[b * NH + t];
      float r = ratings[b * NH + t];
      w = (id != PAD) ? r : 0.f;
    }
    s_ids[t] = id; s_w[t] = w;
    float s = fabsf(w);
    #pragma unroll
    for (int off = 32; off; off >>= 1) s += __shfl_xor(s, off, 64);
    if (t == 0) s_inv = 1.f / fmaxf(s, 1e-6f);
  }
  __syncthreads();
  const float inv = s_inv;

  {  // item pool partials: 2 x 25 gathers per column (256B contig per wave)
    const int c = t & (OD - 1), part = t >> 7;
    float acc = 0.f;
    #pragma unroll
    for (int i = 0; i < 25; ++i) {
      const int h = part * 25 + i;
      acc = fmaf(s_w[h], T[(long)s_ids[h] * OD + c], acc);
    }
    s_part[part][c] = acc;
  }
  __syncthreads();
  if (t < OD) {
    Ucat[(long)b * UC + t] = (__bf16)((s_part[0][t] + s_part[1][t]) * inv);
  } else {
    const int uu = t - 128, col = uu & 15, part = uu >> 4;  // 8 parts x 7 h
    float acc = 0.f;
    #pragma unroll
    for (int i = 0; i < 7; ++i) {
      const int h = part * 7 + i;
      if (h < NH) acc = fmaf(s_w[h], GT[(long)s_ids[h] * EGT + col], acc);
    }
    s_gp[part][col] = acc;
  }
  __syncthreads();
  if (t < EGT) {
    float acc = 0.f;
    #pragma unroll
    for (int p = 0; p < 8; ++p) acc += s_gp[p][t];
    Ucat[(long)b * UC + OD + t] = (__bf16)(acc * inv);
  } else if (t >= 32 && t < 64) {
    const int j = t - 32;
    float a = b_ugenre[j];
    #pragma unroll
    for (int k = 0; k < NGENRES; ++k)
      a = fmaf(ugc[b * NGENRES + k], w_ugenre[k * EUG + j], a);
    Ucat[(long)b * UC + 144 + j] = (__bf16)tanhf(a);     // 128+16
  } else if (t >= 64 && t < 64 + ETS) {
    const int j = t - 64;
    const int ts = tstamps[b];
    float a = b_ts[j];
    #pragma unroll
    for (int k = 0; k < ETS; ++k)
      a = fmaf(ts_tab[ts * ETS + k], w_ts[k * ETS + j], a);
    Ucat[(long)b * UC + 176 + j] = (__bf16)tanhf(a);     // 128+16+32
  } else if (t >= 68 && t < 80) {
    Ucat[(long)b * UC + 180 + (t - 68)] = (__bf16)0.f;   // zero pad
  }
}

// ---------------------------------------------------------------------------
// MLP: user MLP via MFMA + final dot. 64 blocks x 16 users; weights from
// pre-swizzled frag tables (coalesced, L2-hot).
// ---------------------------------------------------------------------------
__global__ __launch_bounds__(256) void user_mlp_kernel(
    const int* __restrict__ target,
    const float* __restrict__ b_up1, const float* __restrict__ b_up2,
    const __bf16* __restrict__ Wup1f, const __bf16* __restrict__ Wup2f,
    const __bf16* __restrict__ Ucat, const float* __restrict__ T,
    float* __restrict__ out)
{
  __shared__ __align__(16) __bf16 s_u[16][UCS];   // 6.4 KB
  __shared__ __align__(16) __bf16 s_h[16][SH];    // 8.4 KB
  __shared__ __align__(16) float  s_e[16][132];   // 8.4 KB
  __shared__ float s_red[2];

  const int t = threadIdx.x, blk = blockIdx.x;
  const int wave = t >> 6, lane = t & 63, l15 = lane & 15, quad = lane >> 4;
  const int u0 = blk * 16;

  {  // stage Ucat tile: 16 thr/user, segs of 8 bf16 (24 segs of 16B)
    const int uu = t >> 4, s = t & 15;
    const __bf16* src = Ucat + (long)(u0 + uu) * UC;
    *(bf16x8*)&s_u[uu][s * 8] = *(const bf16x8*)(src + s * 8);
    if (s < 8)
      *(bf16x8*)&s_u[uu][(s + 16) * 8] = *(const bf16x8*)(src + (s + 16) * 8);
  }
  __syncthreads();

  // ---- up1: [16,192]@[192,256] -> relu -> s_h ----
  {
    bf16x8 af[KC_UP1];
    #pragma unroll
    for (int kc = 0; kc < KC_UP1; ++kc)
      af[kc] = *(const bf16x8*)&s_u[l15][kc * 32 + quad * 8];
    #pragma unroll
    for (int nt = 0; nt < 4; ++nt) {
      const int n = wave * 64 + nt * 16 + l15;
      const float bb = b_up1[n];
      f32x4 acc = {bb, bb, bb, bb};
      #pragma unroll
      for (int kc = 0; kc < KC_UP1; ++kc) {
        bf16x8 bfr = *(const bf16x8*)(Wup1f + ((long)(kc * NT_UP1 + wave * 4 + nt) * 64 + lane) * 8);
        acc = mfma16(af[kc], bfr, acc);
      }
      #pragma unroll
      for (int r2 = 0; r2 < 4; ++r2)
        s_h[quad * 4 + r2][n] = (__bf16)fmaxf(acc[r2], 0.f);
    }
  }
  __syncthreads();

  // ---- up2: [16,256]@[256,128] -> s_e fp32 ----
  {
    bf16x8 af[KC_UP2];
    #pragma unroll
    for (int kc = 0; kc < KC_UP2; ++kc)
      af[kc] = *(const bf16x8*)&s_h[l15][kc * 32 + quad * 8];
    #pragma unroll
    for (int nt = 0; nt < 2; ++nt) {
      const int n = wave * 32 + nt * 16 + l15;
      const float bb = b_up2[n];
      f32x4 acc = {bb, bb, bb, bb};
      #pragma unroll
      for (int kc = 0; kc < KC_UP2; ++kc) {
        bf16x8 bfr = *(const bf16x8*)(Wup2f + ((long)(kc * NT_UP2 + wave * 2 + nt) * 64 + lane) * 8);
        acc = mfma16(af[kc], bfr, acc);
      }
      #pragma unroll
      for (int r2 = 0; r2 < 4; ++r2)
        s_e[quad * 4 + r2][n] = acc[r2];
    }
  }
  __syncthreads();

  // ---- dot(user, T[target]): 8 threads per user ----
  if (t < 128) {
    const int uu = t >> 3, q = t & 7;
    const int tgt = target[u0 + uu];
    const float* trow = T + (long)tgt * OD + q * 16;
    float s = 0.f;
    #pragma unroll
    for (int i = 0; i < 4; ++i) {
      float4 v = *(const float4*)(trow + i * 4);
      f32x4 e = *(const f32x4*)&s_e[uu][q * 16 + i * 4];
      s += v.x * e[0] + v.y * e[1] + v.z * e[2] + v.w * e[3];
    }
    s += __shfl_down(s, 1, 64);
    s += __shfl_down(s, 2, 64);
    s += __shfl_down(s, 4, 64);
    if (q == 0) out[u0 + uu] = s;
  }
  (void)s_red;
}

// ---------------------------------------------------------------------------
extern "C" void kernel_launch(void* const* d_in, const int* in_sizes, int n_in,
                              void* d_out, int out_size, void* d_ws, size_t ws_size,
                              hipStream_t stream) {
  const float* ugc      = (const float*)d_in[0];
  const int*   hist     = (const int*)  d_in[1];
  const float* ratings  = (const float*)d_in[2];
  const int*   tstamps  = (const int*)  d_in[3];
  const int*   target   = (const int*)  d_in[4];
  const float* genome   = (const float*)d_in[5];
  const float* genrec   = (const float*)d_in[6];
  const float* tagc     = (const float*)d_in[7];
  const int*   yearc    = (const int*)  d_in[8];
  const float* item_emb = (const float*)d_in[9];
  const float* year_tab = (const float*)d_in[10];
  const float* ts_tab   = (const float*)d_in[11];
  const float* w_item   = (const float*)d_in[12];
  const float* b_item   = (const float*)d_in[13];
  const float* w_genre  = (const float*)d_in[14];
  const float* b_genre  = (const float*)d_in[15];
  const float* w_tag    = (const float*)d_in[16];
  const float* b_tag    = (const float*)d_in[17];
  const float* w_genome = (const float*)d_in[18];
  const float* b_genome = (const float*)d_in[19];
  const float* w_year   = (const float*)d_in[20];
  const float* b_year   = (const float*)d_in[21];
  const float* w_ugenre = (const float*)d_in[22];
  const float* b_ugenre = (const float*)d_in[23];
  const float* w_ts     = (const float*)d_in[24];
  const float* b_ts     = (const float*)d_in[25];
  const float* w_up1    = (const float*)d_in[26];
  const float* b_up1    = (const float*)d_in[27];
  const float* w_up2    = (const float*)d_in[28];
  const float* b_up2    = (const float*)d_in[29];
  const float* w_ip1    = (const float*)d_in[30];
  const float* b_ip1    = (const float*)d_in[31];
  const float* w_ip2    = (const float*)d_in[32];
  const float* b_ip2    = (const float*)d_in[33];

  char* ws = (char*)d_ws;
  size_t off = 0;
  float*  T     = (float*) (ws + off); off += (size_t)PROWS * OD * 4;     // 10.25 MB
  float*  GT    = (float*) (ws + off); off += (size_t)PROWS * EGT * 4;    // 1.28 MB
  __bf16* Ucat  = (__bf16*)(ws + off); off += (size_t)NB * UC * 2;        // 0.39 MB
  __bf16* Wtf   = (__bf16*)(ws + off); off += (size_t)KC_TAG * 512 * 2;
  __bf16* Wgf   = (__bf16*)(ws + off); off += (size_t)KC_GEN * 512 * 2;
  __bf16* Wip1f = (__bf16*)(ws + off); off += (size_t)KC_IP1 * NT_IP1 * 512 * 2;
  __bf16* Wip2f = (__bf16*)(ws + off); off += (size_t)KC_IP2 * NT_IP2 * 512 * 2;
  __bf16* Wup1f = (__bf16*)(ws + off); off += (size_t)KC_UP1 * NT_UP1 * 512 * 2;
  __bf16* Wup2f = (__bf16*)(ws + off); off += (size_t)KC_UP2 * NT_UP2 * 512 * 2;

  setup_wf_kernel<<<dim3(340), dim3(512), 0, stream>>>(
      w_tag, w_genome, w_ip1, w_ip2, w_up1, w_up2,
      Wtf, Wgf, Wip1f, Wip2f, Wup1f, Wup2f);

  tower_kernel<<<dim3(NT_TILE), dim3(256), 0, stream>>>(
      tagc, genome, genrec, yearc, item_emb, year_tab,
      w_genre, b_genre, b_tag, b_genome, w_item, b_item, w_year, b_year,
      b_ip1, b_ip2, Wtf, Wgf, Wip1f, Wip2f, T, GT);

  user_pool_kernel<<<dim3(NB), dim3(256), 0, stream>>>(
      ugc, hist, ratings, tstamps, ts_tab,
      w_ugenre, b_ugenre, w_ts, b_ts, T, GT, Ucat);

  user_mlp_kernel<<<dim3(NB / 16), dim3(256), 0, stream>>>(
      target, b_up1, b_up2, Wup1f, Wup2f, Ucat, T, (float*)d_out);
}